// Round 1
// baseline (198.901 us; speedup 1.0000x reference)
//
#include <hip/hip_runtime.h>
#include <hip/hip_bf16.h>

// MPNN: B=8, N=36, H=64, STEPS=5
// messages[b,j,k] = (1/N^2) * sum_{i,l} edge[b,i,j,k,l] * nodes[b,i,l]
// nodes = GRUCell(messages, nodes) * mask, repeated STEPS times.

#define BB 8
#define NN 36
#define HH 64
#define GG 6            // i-groups per (b,j) for the einsum split
#define IPG (NN / GG)   // 6 i per group
#define NSTEPS 5

// ---------------------------------------------------------------------------
// Kernel A: partial einsum.
// grid = BB*NN*GG blocks of 64 threads (1 wave). bid = (b*NN + j)*GG + g.
// lane = k. partial[bid*HH + k] = sum_{i in group, l} edge[b,i,j,k,l]*nodes[b,i,l]
// ---------------------------------------------------------------------------
__global__ __launch_bounds__(64) void einsum_partial(
    const float* __restrict__ edge,
    const float* __restrict__ nodes,
    float* __restrict__ partial)
{
    const int lane = threadIdx.x;        // k
    const int bid  = blockIdx.x;
    const int g = bid % GG;
    const int j = (bid / GG) % NN;
    const int b = bid / (GG * NN);

    __shared__ float nd[IPG * HH];
    #pragma unroll
    for (int ii = 0; ii < IPG; ++ii) {
        const int i = g * IPG + ii;
        nd[ii * HH + lane] = nodes[(b * NN + i) * HH + lane];
    }
    __syncthreads();

    float acc = 0.f;
    for (int ii = 0; ii < IPG; ++ii) {
        const int i = g * IPG + ii;
        // edge[b][i][j][k=lane][l], row of 64 floats = 256 B contiguous
        const float4* __restrict__ wrow =
            (const float4*)(edge + (((size_t)(b * NN + i) * NN + j) * HH + lane) * HH);
        #pragma unroll
        for (int l4 = 0; l4 < HH / 4; ++l4) {
            const float4 w = wrow[l4];
            const float4 v = *(const float4*)&nd[ii * HH + l4 * 4];
            acc = fmaf(w.x, v.x, acc);
            acc = fmaf(w.y, v.y, acc);
            acc = fmaf(w.z, v.z, acc);
            acc = fmaf(w.w, v.w, acc);
        }
    }
    partial[(size_t)bid * HH + lane] = acc;
}

// ---------------------------------------------------------------------------
// Kernel B: reduce partials + GRU cell + mask.
// grid = BB*NN blocks of 64 threads. bj = b*NN + j, t = k.
// ---------------------------------------------------------------------------
__global__ __launch_bounds__(64) void gru_step(
    const float* __restrict__ partial,
    const float* __restrict__ nodes_in,
    const float* __restrict__ mask,
    const float* __restrict__ w_ih,
    const float* __restrict__ w_hh,
    const float* __restrict__ b_ih,
    const float* __restrict__ b_hh,
    float* __restrict__ nodes_out)
{
    const int t  = threadIdx.x;
    const int bj = blockIdx.x;
    const float inv_n2 = 1.0f / (float)(NN * NN);

    float m = 0.f;
    #pragma unroll
    for (int g = 0; g < GG; ++g)
        m += partial[((size_t)bj * GG + g) * HH + t];
    m *= inv_n2;
    const float h = nodes_in[bj * HH + t];

    __shared__ float ms[HH];
    __shared__ float hs[HH];
    ms[t] = m;
    hs[t] = h;
    __syncthreads();

    // thread t computes gate rows t (reset), t+64 (update), t+128 (new)
    float gi0 = b_ih[t], gi1 = b_ih[HH + t], gi2 = b_ih[2 * HH + t];
    float gh0 = b_hh[t], gh1 = b_hh[HH + t], gh2 = b_hh[2 * HH + t];

    const float4* __restrict__ wi0 = (const float4*)(w_ih + (0 * HH + t) * HH);
    const float4* __restrict__ wi1 = (const float4*)(w_ih + (1 * HH + t) * HH);
    const float4* __restrict__ wi2 = (const float4*)(w_ih + (2 * HH + t) * HH);
    const float4* __restrict__ wh0 = (const float4*)(w_hh + (0 * HH + t) * HH);
    const float4* __restrict__ wh1 = (const float4*)(w_hh + (1 * HH + t) * HH);
    const float4* __restrict__ wh2 = (const float4*)(w_hh + (2 * HH + t) * HH);

    #pragma unroll
    for (int k4 = 0; k4 < HH / 4; ++k4) {
        const float4 mv = *(const float4*)&ms[k4 * 4];
        const float4 hv = *(const float4*)&hs[k4 * 4];
        float4 a;
        a = wi0[k4]; gi0 += a.x * mv.x + a.y * mv.y + a.z * mv.z + a.w * mv.w;
        a = wi1[k4]; gi1 += a.x * mv.x + a.y * mv.y + a.z * mv.z + a.w * mv.w;
        a = wi2[k4]; gi2 += a.x * mv.x + a.y * mv.y + a.z * mv.z + a.w * mv.w;
        a = wh0[k4]; gh0 += a.x * hv.x + a.y * hv.y + a.z * hv.z + a.w * hv.w;
        a = wh1[k4]; gh1 += a.x * hv.x + a.y * hv.y + a.z * hv.z + a.w * hv.w;
        a = wh2[k4]; gh2 += a.x * hv.x + a.y * hv.y + a.z * hv.z + a.w * hv.w;
    }

    const float r = 1.f / (1.f + expf(-(gi0 + gh0)));
    const float z = 1.f / (1.f + expf(-(gi1 + gh1)));
    const float n = tanhf(gi2 + r * gh2);
    float outv = (1.f - z) * n + z * h;
    outv *= mask[bj];
    nodes_out[bj * HH + t] = outv;
}

extern "C" void kernel_launch(void* const* d_in, const int* in_sizes, int n_in,
                              void* d_out, int out_size, void* d_ws, size_t ws_size,
                              hipStream_t stream) {
    const float* edge   = (const float*)d_in[0];
    const float* nodes0 = (const float*)d_in[1];
    const float* mask   = (const float*)d_in[2];
    const float* w_ih   = (const float*)d_in[3];
    const float* w_hh   = (const float*)d_in[4];
    const float* b_ih   = (const float*)d_in[5];
    const float* b_hh   = (const float*)d_in[6];
    float* out = (float*)d_out;

    float* ws = (float*)d_ws;
    const int nodes_elems = BB * NN * HH;                 // 18432
    float* nodesA  = ws;
    float* nodesB  = ws + nodes_elems;
    float* partial = ws + 2 * nodes_elems;                // BB*NN*GG*HH = 110592 floats

    const float* cur = nodes0;
    for (int s = 0; s < NSTEPS; ++s) {
        einsum_partial<<<BB * NN * GG, 64, 0, stream>>>(edge, cur, partial);
        float* nxt = (s == NSTEPS - 1) ? out : ((s & 1) ? nodesB : nodesA);
        gru_step<<<BB * NN, 64, 0, stream>>>(partial, cur, mask,
                                             w_ih, w_hh, b_ih, b_hh, nxt);
        cur = nxt;
    }
}

// Round 2
// 176.519 us; speedup vs baseline: 1.1268x; 1.1268x over previous
//
#include <hip/hip_runtime.h>
#include <hip/hip_bf16.h>

// MPNN: B=8, N=36, H=64, STEPS=5
// messages[b,j,k] = (1/N^2) * sum_{i,l} edge[b,i,j,k,l] * nodes[b,i,l]
// nodes = GRUCell(messages, nodes) * mask, repeated STEPS times.

#define BB 8
#define NN 36
#define HH 64
#define GG 6            // i-groups per (b,j) for the einsum split
#define IPG (NN / GG)   // 6 i per group
#define NSTEPS 5

// ---------------------------------------------------------------------------
// Kernel A: partial einsum, fully-coalesced edge reads.
// grid = BB*NN*GG blocks of 64 threads (1 wave). bid = (b*NN + j)*GG + g.
// Each (b,i,j) edge block is 64x64 f32 = 1024 float4. Lane reads
// flat4 = it*64 + lane  (consecutive lanes -> consecutive 16B: coalesced).
//   k  = flat4/16 = 4*it + lane/16
//   l4 = flat4%16 = lane%16          (fixed per lane)
// Lane accumulates acc[it] (static index -> registers). Butterfly over the
// low 4 lane bits sums the 16 l4-partials per k; lane (g=lane>>4, p=lane&15)
// then writes k = 4*p + g via a static select chain.
// ---------------------------------------------------------------------------
__global__ __launch_bounds__(64) void einsum_partial(
    const float* __restrict__ edge,
    const float* __restrict__ nodes,
    float* __restrict__ partial)
{
    const int lane = threadIdx.x;
    const int bid  = blockIdx.x;
    const int g = bid % GG;
    const int j = (bid / GG) % NN;
    const int b = bid / (GG * NN);

    const int l4 = lane & 15;

    float acc[16];
    #pragma unroll
    for (int it = 0; it < 16; ++it) acc[it] = 0.f;

    #pragma unroll
    for (int ii = 0; ii < IPG; ++ii) {
        const int i = g * IPG + ii;
        const float4 v = *(const float4*)(nodes + (b * NN + i) * HH + l4 * 4);
        const float4* __restrict__ Wb =
            (const float4*)(edge + ((size_t)((b * NN + i) * NN + j)) * (HH * HH));
        #pragma unroll
        for (int it = 0; it < 16; ++it) {
            const float4 w = Wb[it * 64 + lane];
            acc[it] = fmaf(w.x, v.x, acc[it]);
            acc[it] = fmaf(w.y, v.y, acc[it]);
            acc[it] = fmaf(w.z, v.z, acc[it]);
            acc[it] = fmaf(w.w, v.w, acc[it]);
        }
    }

    // reduce the 16 l4-partials across each 16-lane group (low 4 lane bits)
    #pragma unroll
    for (int m = 1; m < 16; m <<= 1) {
        #pragma unroll
        for (int it = 0; it < 16; ++it)
            acc[it] += __shfl_xor(acc[it], m, 64);
    }

    // lane (gq = lane>>4, p = lane&15) writes k = 4*p + gq = acc[p]
    const int p  = lane & 15;
    const int gq = lane >> 4;
    float outv = acc[0];
    #pragma unroll
    for (int t = 1; t < 16; ++t) outv = (p == t) ? acc[t] : outv;

    partial[(size_t)bid * HH + (4 * p + gq)] = outv;
}

// ---------------------------------------------------------------------------
// Kernel B: reduce partials + GRU cell + mask.
// grid = BB*NN blocks of 64 threads. bj = b*NN + j, t = k.
// ---------------------------------------------------------------------------
__global__ __launch_bounds__(64) void gru_step(
    const float* __restrict__ partial,
    const float* __restrict__ nodes_in,
    const float* __restrict__ mask,
    const float* __restrict__ w_ih,
    const float* __restrict__ w_hh,
    const float* __restrict__ b_ih,
    const float* __restrict__ b_hh,
    float* __restrict__ nodes_out)
{
    const int t  = threadIdx.x;
    const int bj = blockIdx.x;
    const float inv_n2 = 1.0f / (float)(NN * NN);

    float m = 0.f;
    #pragma unroll
    for (int g = 0; g < GG; ++g)
        m += partial[((size_t)bj * GG + g) * HH + t];
    m *= inv_n2;
    const float h = nodes_in[bj * HH + t];

    __shared__ float ms[HH];
    __shared__ float hs[HH];
    ms[t] = m;
    hs[t] = h;
    __syncthreads();

    // thread t computes gate rows t (reset), t+64 (update), t+128 (new)
    float gi0 = b_ih[t], gi1 = b_ih[HH + t], gi2 = b_ih[2 * HH + t];
    float gh0 = b_hh[t], gh1 = b_hh[HH + t], gh2 = b_hh[2 * HH + t];

    const float4* __restrict__ wi0 = (const float4*)(w_ih + (0 * HH + t) * HH);
    const float4* __restrict__ wi1 = (const float4*)(w_ih + (1 * HH + t) * HH);
    const float4* __restrict__ wi2 = (const float4*)(w_ih + (2 * HH + t) * HH);
    const float4* __restrict__ wh0 = (const float4*)(w_hh + (0 * HH + t) * HH);
    const float4* __restrict__ wh1 = (const float4*)(w_hh + (1 * HH + t) * HH);
    const float4* __restrict__ wh2 = (const float4*)(w_hh + (2 * HH + t) * HH);

    #pragma unroll
    for (int k4 = 0; k4 < HH / 4; ++k4) {
        const float4 mv = *(const float4*)&ms[k4 * 4];
        const float4 hv = *(const float4*)&hs[k4 * 4];
        float4 a;
        a = wi0[k4]; gi0 += a.x * mv.x + a.y * mv.y + a.z * mv.z + a.w * mv.w;
        a = wi1[k4]; gi1 += a.x * mv.x + a.y * mv.y + a.z * mv.z + a.w * mv.w;
        a = wi2[k4]; gi2 += a.x * mv.x + a.y * mv.y + a.z * mv.z + a.w * mv.w;
        a = wh0[k4]; gh0 += a.x * hv.x + a.y * hv.y + a.z * hv.z + a.w * hv.w;
        a = wh1[k4]; gh1 += a.x * hv.x + a.y * hv.y + a.z * hv.z + a.w * hv.w;
        a = wh2[k4]; gh2 += a.x * hv.x + a.y * hv.y + a.z * hv.z + a.w * hv.w;
    }

    const float r = 1.f / (1.f + expf(-(gi0 + gh0)));
    const float z = 1.f / (1.f + expf(-(gi1 + gh1)));
    const float n = tanhf(gi2 + r * gh2);
    float outv = (1.f - z) * n + z * h;
    outv *= mask[bj];
    nodes_out[bj * HH + t] = outv;
}

extern "C" void kernel_launch(void* const* d_in, const int* in_sizes, int n_in,
                              void* d_out, int out_size, void* d_ws, size_t ws_size,
                              hipStream_t stream) {
    const float* edge   = (const float*)d_in[0];
    const float* nodes0 = (const float*)d_in[1];
    const float* mask   = (const float*)d_in[2];
    const float* w_ih   = (const float*)d_in[3];
    const float* w_hh   = (const float*)d_in[4];
    const float* b_ih   = (const float*)d_in[5];
    const float* b_hh   = (const float*)d_in[6];
    float* out = (float*)d_out;

    float* ws = (float*)d_ws;
    const int nodes_elems = BB * NN * HH;                 // 18432
    float* nodesA  = ws;
    float* nodesB  = ws + nodes_elems;
    float* partial = ws + 2 * nodes_elems;                // BB*NN*GG*HH = 110592 floats

    const float* cur = nodes0;
    for (int s = 0; s < NSTEPS; ++s) {
        einsum_partial<<<BB * NN * GG, 64, 0, stream>>>(edge, cur, partial);
        float* nxt = (s == NSTEPS - 1) ? out : ((s & 1) ? nodesB : nodesA);
        gru_step<<<BB * NN, 64, 0, stream>>>(partial, cur, mask,
                                             w_ih, w_hh, b_ih, b_hh, nxt);
        cur = nxt;
    }
}

// Round 3
// 151.283 us; speedup vs baseline: 1.3148x; 1.1668x over previous
//
#include <hip/hip_runtime.h>
#include <hip/hip_bf16.h>

// MPNN: B=8, N=36, H=64, STEPS=5
// messages[b,j,k] = (1/N^2) * sum_{i,l} edge[b,i,j,k,l] * nodes[b,i,l]
// nodes = GRUCell(messages, nodes) * mask, repeated STEPS times.
//
// Strategy: step 1 streams the f32 edge tensor (170 MB) computing messages AND
// writes a bf16 copy (85 MB) into d_ws. Steps 2-5 stream the bf16 copy only.
// Byte budget: 255 + 4*85 = 595 MB vs 850 MB all-f32.

#define BB 8
#define NN 36
#define HH 64
#define GG 12           // i-groups per (b,j) for the einsum split
#define IPG (NN / GG)   // 3 i per group
#define NSTEPS 5

__device__ __forceinline__ unsigned bf16rtn(float f) {
    unsigned u = __float_as_uint(f);
    return (u + 0x7FFFu + ((u >> 16) & 1u)) >> 16;
}

// ---------------------------------------------------------------------------
// Kernel A1 (step 1): partial einsum on f32 edge + emit bf16 edge copy.
// grid = BB*NN*GG blocks of 64 threads. bid = (b*NN + j)*GG + g.
// Each (b,i,j) edge block is 64x64 f32 = 1024 float4 chunks. Lane reads
// chunk c = it*64 + lane (coalesced 1KB/instr); k = 4*it + lane/16,
// l4 = lane%16. acc[16] static -> registers. 4-stage butterfly over low 4
// lane bits reduces the 16 l-partials; lane (p=lane&15,gq=lane>>4) writes
// k = 4*p+gq. Each loaded float4 is also converted RTN to 4 bf16 and stored
// as uint2 (8B) at the matching flat element offset in the bf16 copy.
// ---------------------------------------------------------------------------
__global__ __launch_bounds__(64) void einsum_f32_cvt(
    const float* __restrict__ edge,
    const float* __restrict__ nodes,
    float* __restrict__ partial,
    uint2* __restrict__ ebf)            // bf16 edge copy, 8B per 4 elems
{
    const int lane = threadIdx.x;
    const int bid  = blockIdx.x;
    const int g = bid % GG;
    const int j = (bid / GG) % NN;
    const int b = bid / (GG * NN);

    const int l4 = lane & 15;

    float acc[16];
    #pragma unroll
    for (int it = 0; it < 16; ++it) acc[it] = 0.f;

    #pragma unroll
    for (int ii = 0; ii < IPG; ++ii) {
        const int i = g * IPG + ii;
        const float4 v = *(const float4*)(nodes + (b * NN + i) * HH + l4 * 4);
        const size_t blkElem = (size_t)((b * NN + i) * NN + j) * (HH * HH);
        const float4* __restrict__ Wb = (const float4*)(edge + blkElem);
        uint2* __restrict__ Eb = ebf + (blkElem >> 2);
        #pragma unroll
        for (int it = 0; it < 16; ++it) {
            const float4 w = Wb[it * 64 + lane];
            acc[it] = fmaf(w.x, v.x, acc[it]);
            acc[it] = fmaf(w.y, v.y, acc[it]);
            acc[it] = fmaf(w.z, v.z, acc[it]);
            acc[it] = fmaf(w.w, v.w, acc[it]);
            uint2 pk;
            pk.x = bf16rtn(w.x) | (bf16rtn(w.y) << 16);
            pk.y = bf16rtn(w.z) | (bf16rtn(w.w) << 16);
            Eb[it * 64 + lane] = pk;
        }
    }

    #pragma unroll
    for (int m = 1; m < 16; m <<= 1) {
        #pragma unroll
        for (int it = 0; it < 16; ++it)
            acc[it] += __shfl_xor(acc[it], m, 64);
    }

    const int p  = lane & 15;
    const int gq = lane >> 4;
    float outv = acc[0];
    #pragma unroll
    for (int t = 1; t < 16; ++t) outv = (p == t) ? acc[t] : outv;

    partial[(size_t)bid * HH + (4 * p + gq)] = outv;
}

// ---------------------------------------------------------------------------
// Kernel A2 (steps 2..5): partial einsum on bf16 edge copy.
// Each (b,i,j) block is 64x64 bf16 = 512 16B chunks (8 elems each).
// Lane reads chunk c = it*64 + lane, it=0..7: k = 8*it + lane/8,
// l8 = lane&7 (lane covers l = 8*l8 .. 8*l8+7). acc[8] static.
// 3-stage butterfly over low 3 lane bits; lane (p=lane&7, gq=lane>>3)
// writes k = 8*p + gq.
// ---------------------------------------------------------------------------
__global__ __launch_bounds__(64) void einsum_bf16(
    const uint4* __restrict__ ebf,      // 16B = 8 bf16
    const float* __restrict__ nodes,
    float* __restrict__ partial)
{
    const int lane = threadIdx.x;
    const int bid  = blockIdx.x;
    const int g = bid % GG;
    const int j = (bid / GG) % NN;
    const int b = bid / (GG * NN);

    const int l8 = lane & 7;

    float acc[8];
    #pragma unroll
    for (int it = 0; it < 8; ++it) acc[it] = 0.f;

    #pragma unroll
    for (int ii = 0; ii < IPG; ++ii) {
        const int i = g * IPG + ii;
        const float* np_ = nodes + (b * NN + i) * HH + l8 * 8;
        const float4 v0 = *(const float4*)(np_);
        const float4 v1 = *(const float4*)(np_ + 4);
        const size_t blkElem = (size_t)((b * NN + i) * NN + j) * (HH * HH);
        const uint4* __restrict__ Wb = ebf + (blkElem >> 3);
        #pragma unroll
        for (int it = 0; it < 8; ++it) {
            const uint4 w = Wb[it * 64 + lane];
            acc[it] = fmaf(__uint_as_float(w.x << 16),          v0.x, acc[it]);
            acc[it] = fmaf(__uint_as_float(w.x & 0xffff0000u),  v0.y, acc[it]);
            acc[it] = fmaf(__uint_as_float(w.y << 16),          v0.z, acc[it]);
            acc[it] = fmaf(__uint_as_float(w.y & 0xffff0000u),  v0.w, acc[it]);
            acc[it] = fmaf(__uint_as_float(w.z << 16),          v1.x, acc[it]);
            acc[it] = fmaf(__uint_as_float(w.z & 0xffff0000u),  v1.y, acc[it]);
            acc[it] = fmaf(__uint_as_float(w.w << 16),          v1.z, acc[it]);
            acc[it] = fmaf(__uint_as_float(w.w & 0xffff0000u),  v1.w, acc[it]);
        }
    }

    #pragma unroll
    for (int m = 1; m < 8; m <<= 1) {
        #pragma unroll
        for (int it = 0; it < 8; ++it)
            acc[it] += __shfl_xor(acc[it], m, 64);
    }

    const int p  = lane & 7;
    const int gq = lane >> 3;
    float outv = acc[0];
    #pragma unroll
    for (int t = 1; t < 8; ++t) outv = (p == t) ? acc[t] : outv;

    partial[(size_t)bid * HH + (8 * p + gq)] = outv;
}

// ---------------------------------------------------------------------------
// Kernel B: reduce partials + GRU cell + mask.
// grid = BB*NN blocks of 64 threads. bj = b*NN + j, t = k.
// ---------------------------------------------------------------------------
__global__ __launch_bounds__(64) void gru_step(
    const float* __restrict__ partial,
    const float* __restrict__ nodes_in,
    const float* __restrict__ mask,
    const float* __restrict__ w_ih,
    const float* __restrict__ w_hh,
    const float* __restrict__ b_ih,
    const float* __restrict__ b_hh,
    float* __restrict__ nodes_out)
{
    const int t  = threadIdx.x;
    const int bj = blockIdx.x;
    const float inv_n2 = 1.0f / (float)(NN * NN);

    float m = 0.f;
    #pragma unroll
    for (int g = 0; g < GG; ++g)
        m += partial[((size_t)bj * GG + g) * HH + t];
    m *= inv_n2;
    const float h = nodes_in[bj * HH + t];

    __shared__ float ms[HH];
    __shared__ float hs[HH];
    ms[t] = m;
    hs[t] = h;
    __syncthreads();

    float gi0 = b_ih[t], gi1 = b_ih[HH + t], gi2 = b_ih[2 * HH + t];
    float gh0 = b_hh[t], gh1 = b_hh[HH + t], gh2 = b_hh[2 * HH + t];

    const float4* __restrict__ wi0 = (const float4*)(w_ih + (0 * HH + t) * HH);
    const float4* __restrict__ wi1 = (const float4*)(w_ih + (1 * HH + t) * HH);
    const float4* __restrict__ wi2 = (const float4*)(w_ih + (2 * HH + t) * HH);
    const float4* __restrict__ wh0 = (const float4*)(w_hh + (0 * HH + t) * HH);
    const float4* __restrict__ wh1 = (const float4*)(w_hh + (1 * HH + t) * HH);
    const float4* __restrict__ wh2 = (const float4*)(w_hh + (2 * HH + t) * HH);

    #pragma unroll
    for (int k4 = 0; k4 < HH / 4; ++k4) {
        const float4 mv = *(const float4*)&ms[k4 * 4];
        const float4 hv = *(const float4*)&hs[k4 * 4];
        float4 a;
        a = wi0[k4]; gi0 += a.x * mv.x + a.y * mv.y + a.z * mv.z + a.w * mv.w;
        a = wi1[k4]; gi1 += a.x * mv.x + a.y * mv.y + a.z * mv.z + a.w * mv.w;
        a = wi2[k4]; gi2 += a.x * mv.x + a.y * mv.y + a.z * mv.z + a.w * mv.w;
        a = wh0[k4]; gh0 += a.x * hv.x + a.y * hv.y + a.z * hv.z + a.w * hv.w;
        a = wh1[k4]; gh1 += a.x * hv.x + a.y * hv.y + a.z * hv.z + a.w * hv.w;
        a = wh2[k4]; gh2 += a.x * hv.x + a.y * hv.y + a.z * hv.z + a.w * hv.w;
    }

    const float r = 1.f / (1.f + expf(-(gi0 + gh0)));
    const float z = 1.f / (1.f + expf(-(gi1 + gh1)));
    const float n = tanhf(gi2 + r * gh2);
    float outv = (1.f - z) * n + z * h;
    outv *= mask[bj];
    nodes_out[bj * HH + t] = outv;
}

extern "C" void kernel_launch(void* const* d_in, const int* in_sizes, int n_in,
                              void* d_out, int out_size, void* d_ws, size_t ws_size,
                              hipStream_t stream) {
    const float* edge   = (const float*)d_in[0];
    const float* nodes0 = (const float*)d_in[1];
    const float* mask   = (const float*)d_in[2];
    const float* w_ih   = (const float*)d_in[3];
    const float* w_hh   = (const float*)d_in[4];
    const float* b_ih   = (const float*)d_in[5];
    const float* b_hh   = (const float*)d_in[6];
    float* out = (float*)d_out;

    float* ws = (float*)d_ws;
    const int nodes_elems = BB * NN * HH;                  // 18432
    float* nodesA  = ws;                                   // 18432 f
    float* nodesB  = ws + nodes_elems;                     // 18432 f
    float* partial = ws + 2 * nodes_elems;                 // BB*NN*GG*HH = 221184 f
    float* ebf_f   = partial + (size_t)BB * NN * GG * HH;  // bf16 edge copy, ~88.5 MB
    uint2* ebf2 = (uint2*)ebf_f;
    const uint4* ebf4 = (const uint4*)ebf_f;

    const int grid_e = BB * NN * GG;   // 3456

    const float* cur = nodes0;
    for (int s = 0; s < NSTEPS; ++s) {
        if (s == 0)
            einsum_f32_cvt<<<grid_e, 64, 0, stream>>>(edge, cur, partial, ebf2);
        else
            einsum_bf16<<<grid_e, 64, 0, stream>>>(ebf4, cur, partial);
        float* nxt = (s == NSTEPS - 1) ? out : ((s & 1) ? nodesB : nodesA);
        gru_step<<<BB * NN, 64, 0, stream>>>(partial, cur, mask,
                                             w_ih, w_hh, b_ih, b_hh, nxt);
        cur = nxt;
    }
}